// Round 1
// baseline (425.299 us; speedup 1.0000x reference)
//
#include <hip/hip_runtime.h>
#include <hip/hip_bf16.h>

// Problem constants
#define D_DIM   25088
#define B_ROWS  2048
#define C_CLS   100
#define NT      7            // 7 tiles of 16 cols -> 112 padded classes
#define NPAD    112
#define KSTEPS_TOTAL 784     // 25088 / 32
#define SPLITS  56
#define KSTEPS_PER (KSTEPS_TOTAL / SPLITS)  // 14
#define EPS     1e-8f

typedef __bf16 bf16x8 __attribute__((ext_vector_type(8)));
typedef float  f32x4  __attribute__((ext_vector_type(4)));
typedef float  f32x2  __attribute__((ext_vector_type(2)));

// RNE float->bf16, pack two into one dword
__device__ __forceinline__ unsigned bfpack2(float lo, float hi) {
    unsigned a = __builtin_bit_cast(unsigned, lo);
    unsigned b = __builtin_bit_cast(unsigned, hi);
    a += 0x7FFFu + ((a >> 16) & 1u);
    b += 0x7FFFu + ((b >> 16) & 1u);
    return (a >> 16) | (b & 0xFFFF0000u);
}

// ---------------- prep: per-class norm + pack weight into MFMA B-fragment order ----
// Grid (NPAD, 7): block (c, by) handles 7 of the 49 512-float chunks of class row c.
// Per-class sumsq accumulated via one atomicAdd per block into wnorm2[c].
// wpack layout: unit u = gstep*7 + t; lane l = quad*16 + n holds
//   B[k = gstep*32 + quad*8 + j][col = t*16 + n], j=0..7, as 8 bf16 (uint4).
__global__ __launch_bounds__(256) void prep_kernel(const float* __restrict__ w,
                                                   float* __restrict__ wnorm2,
                                                   unsigned* __restrict__ wpack) {
    int c = blockIdx.x;              // 0..111
    int t = c >> 4, n = c & 15;
    bool real = (c < C_CLS);
    const float* row = w + (size_t)c * D_DIM;
    float s = 0.f;
    int i0 = blockIdx.y * 7;
#pragma unroll
    for (int ii = 0; ii < 7; ++ii) {
        int d = (i0 + ii) * 512 + threadIdx.x * 2;
        f32x2 v = {0.f, 0.f};
        if (real) v = *(const f32x2*)(row + d);
        s += v[0]*v[0] + v[1]*v[1];
        int gstep = d >> 5, r = d & 31, quad = r >> 3, j = r & 7;
        unsigned dw = bfpack2(v[0], v[1]);
        size_t idx = ((size_t)(gstep * 7 + t) * 64 + quad * 16 + n) * 4 + (j >> 1);
        wpack[idx] = dw;
    }
    if (!real) return;
    __shared__ float red[4];
    for (int o = 32; o; o >>= 1) s += __shfl_down(s, o, 64);
    if ((threadIdx.x & 63) == 0) red[threadIdx.x >> 6] = s;
    __syncthreads();
    if (threadIdx.x == 0) atomicAdd(&wnorm2[c], red[0] + red[1] + red[2] + red[3]);
}

// ---------------- main GEMM: dot(f_b, w_c) + sumsq(f_b), split-K atomics ----------------
// launch_bounds(256, 8): VGPR_Count was 44 -> fits 8 waves/SIMD; grid 1792 blocks = 7/CU
// all co-resident -> ~2x the latency-hiding TLP vs the previous (256,4) cap.
__global__ __launch_bounds__(256, 8) void gemm_kernel(const float* __restrict__ feat,
                                                      const uint4* __restrict__ wpack,
                                                      float* __restrict__ pred,
                                                      float* __restrict__ fnorm2) {
    int tid  = threadIdx.x;
    int wave = tid >> 6, lane = tid & 63;
    int m = lane & 15, quad = lane >> 4;
    int rowbase = blockIdx.x * 64 + wave * 16;
    int row = rowbase + m;
    int gstep0 = blockIdx.y * KSTEPS_PER;

    const float* pA = feat + (size_t)row * D_DIM + gstep0 * 32 + quad * 8;
    const uint4* pB = wpack + (size_t)gstep0 * NT * 64 + lane;

    f32x4 acc[NT];
#pragma unroll
    for (int t = 0; t < NT; ++t) acc[t] = (f32x4){0.f,0.f,0.f,0.f};
    float sumsq = 0.f;

    f32x4 a0 = *(const f32x4*)(pA);
    f32x4 a1 = *(const f32x4*)(pA + 4);

    for (int s = 0; s < KSTEPS_PER; ++s) {
        // prefetch next step's A (clamped on last iter to avoid OOB)
        const float* pn = pA + ((s + 1 < KSTEPS_PER) ? 32 : 0);
        f32x4 n0 = *(const f32x4*)(pn);
        f32x4 n1 = *(const f32x4*)(pn + 4);

        sumsq += a0[0]*a0[0] + a0[1]*a0[1] + a0[2]*a0[2] + a0[3]*a0[3]
               + a1[0]*a1[0] + a1[1]*a1[1] + a1[2]*a1[2] + a1[3]*a1[3];
        uint4 ap;
        ap.x = bfpack2(a0[0], a0[1]);
        ap.y = bfpack2(a0[2], a0[3]);
        ap.z = bfpack2(a1[0], a1[1]);
        ap.w = bfpack2(a1[2], a1[3]);
        bf16x8 afrag = __builtin_bit_cast(bf16x8, ap);
#pragma unroll
        for (int t = 0; t < NT; ++t) {
            bf16x8 bfrag = __builtin_bit_cast(bf16x8, pB[t * 64]);
            acc[t] = __builtin_amdgcn_mfma_f32_16x16x32_bf16(afrag, bfrag, acc[t], 0, 0, 0);
        }
        a0 = n0; a1 = n1;
        pA += 32;
        pB += NT * 64;
    }

    // sumsq: reduce across the 4 quads that share row m
    sumsq += __shfl_xor(sumsq, 16, 64);
    sumsq += __shfl_xor(sumsq, 32, 64);
    if (quad == 0) atomicAdd(&fnorm2[row], sumsq);

    // C/D layout (16x16x32 bf16): col = lane&15, row = quad*4 + reg
#pragma unroll
    for (int t = 0; t < NT; ++t) {
#pragma unroll
        for (int r = 0; r < 4; ++r) {
            int orow = rowbase + quad * 4 + r;
            int ocol = t * 16 + m;
            atomicAdd(&pred[(size_t)orow * NPAD + ocol], acc[t][r]);
        }
    }
}

// ---------------- per-row log-softmax / NLL / argmax: one wave per row ----------------
// Grid must cover all B_ROWS waves: 2048 rows / 4 rows-per-block = 512 blocks.
// label dtype (int32 vs int64) dispatched at launch from in_sizes.
__global__ __launch_bounds__(256) void finalize_kernel(const float* __restrict__ pred,
                                                       const float* __restrict__ fnorm2,
                                                       const float* __restrict__ wnorm2,
                                                       const void* __restrict__ labp,
                                                       int lab64,
                                                       float* __restrict__ scal) {
    int gwave = (blockIdx.x * 256 + threadIdx.x) >> 6;
    int lane = threadIdx.x & 63;
    int row = gwave;
    if (row >= B_ROWS) return;
    float finv = 10.0f / fmaxf(sqrtf(fnorm2[row]), EPS);
    const float* pr = pred + (size_t)row * NPAD;

    int c0 = lane, c1 = lane + 64;
    float l0 = -1e30f, l1 = -1e30f;
    if (c0 < C_CLS) {
        float ws = 1.0f / fmaxf(sqrtf(wnorm2[c0]), EPS);
        l0 = pr[c0] * ws * finv;
    }
    if (c1 < C_CLS) {
        float ws = 1.0f / fmaxf(sqrtf(wnorm2[c1]), EPS);
        l1 = pr[c1] * ws * finv;
    }

    // argmax (first-max tie rule: keep smaller index on ties)
    float mx = l0; int am = c0;
    if (l1 > mx) { mx = l1; am = c1; }
    for (int o = 1; o < 64; o <<= 1) {
        float om = __shfl_xor(mx, o, 64);
        int   oa = __shfl_xor(am, o, 64);
        if (om > mx || (om == mx && oa < am)) { mx = om; am = oa; }
    }
    float se = expf(l0 - mx) + expf(l1 - mx);
    for (int o = 1; o < 64; o <<= 1) se += __shfl_xor(se, o, 64);

    int lab = lab64 ? (int)((const long long*)labp)[row] : ((const int*)labp)[row];
    int labc = (lab < 0) ? 0 : lab;
    float lv = (labc >= 64) ? l1 : l0;
    float ll = __shfl(lv, labc & 63, 64);

    if (lane == 0 && lab >= 0) {
        float lse = mx + logf(se);
        atomicAdd(&scal[0], lse - ll);
        atomicAdd(&scal[1], (am == lab) ? 1.f : 0.f);
        atomicAdd(&scal[2], 1.f);
    }
}

__global__ void out_kernel(const float* __restrict__ scal, float* __restrict__ out) {
    out[0] = scal[0] / fmaxf(scal[2], 1.0f);
    out[1] = scal[1] / (scal[2] + 1e-10f);
}

// Workspace layout (bytes):
//   [0, 917504)          pred partials   2048*112 f32   (zeroed)
//   [917504, 925696)     fnorm2          2048 f32       (zeroed)
//   [925696, 925712)     scalars         4 f32          (zeroed, 3 used)
//   [925712, 926160)     wnorm2          112 f32        (zeroed)
//   [926720, 6546432)    wpack bf16 B-fragments (784*7*64 uint4)
extern "C" void kernel_launch(void* const* d_in, const int* in_sizes, int n_in,
                              void* d_out, int out_size, void* d_ws, size_t ws_size,
                              hipStream_t stream) {
    const float* feat   = (const float*)d_in[0];
    const void*  label  = d_in[1];
    const float* weight = (const float*)d_in[2];
    float* out = (float*)d_out;

    char* ws = (char*)d_ws;
    float* pred   = (float*)(ws);
    float* fnorm2 = (float*)(ws + 917504);
    float* scal   = (float*)(ws + 925696);
    float* wnorm2 = (float*)(ws + 925712);
    uint4* wpack  = (uint4*)(ws + 926720);

    int lab64 = (n_in > 1 && in_sizes[1] >= B_ROWS * 8) ? 1 : 0;

    hipMemsetAsync(ws, 0, 926160, stream);
    prep_kernel<<<dim3(NPAD, 7), 256, 0, stream>>>(weight, wnorm2, (unsigned*)wpack);
    gemm_kernel<<<dim3(B_ROWS / 64, SPLITS), 256, 0, stream>>>(feat, wpack, pred, fnorm2);
    finalize_kernel<<<B_ROWS / 4, 256, 0, stream>>>(pred, fnorm2, wnorm2, label, lab64, scal);
    out_kernel<<<1, 1, 0, stream>>>(scal, out);
}

// Round 2
// 416.895 us; speedup vs baseline: 1.0202x; 1.0202x over previous
//
#include <hip/hip_runtime.h>
#include <hip/hip_bf16.h>

// Problem constants
#define D_DIM   25088
#define B_ROWS  2048
#define C_CLS   100
#define NT      7            // 7 tiles of 16 cols -> 112 padded classes
#define NPAD    112
#define KSTEPS_TOTAL 784     // 25088 / 32
#define EPS     1e-8f

typedef __bf16 bf16x8 __attribute__((ext_vector_type(8)));
typedef float  f32x4  __attribute__((ext_vector_type(4)));
typedef float  f32x2  __attribute__((ext_vector_type(2)));

// RNE float->bf16, pack two into one dword
__device__ __forceinline__ unsigned bfpack2(float lo, float hi) {
    unsigned a = __builtin_bit_cast(unsigned, lo);
    unsigned b = __builtin_bit_cast(unsigned, hi);
    a += 0x7FFFu + ((a >> 16) & 1u);
    b += 0x7FFFu + ((b >> 16) & 1u);
    return (a >> 16) | (b & 0xFFFF0000u);
}

// ---------------- prep: per-class norm + pack weight into MFMA B-fragment order ----
// Grid (NPAD, 7): block (c, by) handles 7 of the 49 512-float chunks of class row c.
// Per-class sumsq accumulated via one atomicAdd per block into wnorm2[c].
// wpack layout: unit u = gstep*7 + t; lane l = quad*16 + n holds
//   B[k = gstep*32 + quad*8 + j][col = t*16 + n], j=0..7, as 8 bf16 (uint4).
__global__ __launch_bounds__(256) void prep_kernel(const float* __restrict__ w,
                                                   float* __restrict__ wnorm2,
                                                   unsigned* __restrict__ wpack) {
    int c = blockIdx.x;              // 0..111
    int t = c >> 4, n = c & 15;
    bool real = (c < C_CLS);
    const float* row = w + (size_t)c * D_DIM;
    float s = 0.f;
    int i0 = blockIdx.y * 7;
#pragma unroll
    for (int ii = 0; ii < 7; ++ii) {
        int d = (i0 + ii) * 512 + threadIdx.x * 2;
        f32x2 v = {0.f, 0.f};
        if (real) v = *(const f32x2*)(row + d);
        s += v[0]*v[0] + v[1]*v[1];
        int gstep = d >> 5, r = d & 31, quad = r >> 3, j = r & 7;
        unsigned dw = bfpack2(v[0], v[1]);
        size_t idx = ((size_t)(gstep * 7 + t) * 64 + quad * 16 + n) * 4 + (j >> 1);
        wpack[idx] = dw;
    }
    if (!real) return;
    __shared__ float red[4];
    for (int o = 32; o; o >>= 1) s += __shfl_down(s, o, 64);
    if ((threadIdx.x & 63) == 0) red[threadIdx.x >> 6] = s;
    __syncthreads();
    if (threadIdx.x == 0) atomicAdd(&wnorm2[c], red[0] + red[1] + red[2] + red[3]);
}

// ---------------- main GEMM: dot(f_b, w_c) + sumsq(f_b) ----------------
// Split-K WITHOUT atomics: split sidx writes its partials to a private slab
//   pred2[(sidx*B_ROWS + row)*NPAD + col]  and  fnorm2s[sidx*B_ROWS + row].
// Inner loop manually 2x-unrolled with ping-pong A/B register buffers so the
// next step's 9 loads (2 A f32x4 + 7 B uint4) are in flight during the current
// step's pack+MFMA (~1.5 steps of prefetch distance, no v_mov rotation).
__global__ __launch_bounds__(256, 4) void gemm_kernel(const float* __restrict__ feat,
                                                      const uint4* __restrict__ wpack,
                                                      float* __restrict__ pred2,
                                                      float* __restrict__ fnorm2s,
                                                      int ksteps) {
    int tid  = threadIdx.x;
    int wave = tid >> 6, lane = tid & 63;
    int m = lane & 15, quad = lane >> 4;
    int rowbase = blockIdx.x * 64 + wave * 16;
    int row = rowbase + m;
    int sidx = blockIdx.y;
    int gstep0 = sidx * ksteps;

    const float* pA = feat + (size_t)row * D_DIM + gstep0 * 32 + quad * 8;
    const uint4* pB = wpack + (size_t)gstep0 * NT * 64 + lane;

    f32x4 acc[NT];
#pragma unroll
    for (int t = 0; t < NT; ++t) acc[t] = (f32x4){0.f,0.f,0.f,0.f};
    float sumsq = 0.f;

    // prologue: step-0 operands
    f32x4 a0 = ((const f32x4*)pA)[0], a1 = ((const f32x4*)pA)[1];
    uint4 b[NT];
#pragma unroll
    for (int t = 0; t < NT; ++t) b[t] = pB[t * 64];

#define STEP(A0, A1, B)                                                        \
    do {                                                                       \
        sumsq += A0[0]*A0[0] + A0[1]*A0[1] + A0[2]*A0[2] + A0[3]*A0[3]         \
               + A1[0]*A1[0] + A1[1]*A1[1] + A1[2]*A1[2] + A1[3]*A1[3];        \
        uint4 ap;                                                              \
        ap.x = bfpack2(A0[0], A0[1]);                                          \
        ap.y = bfpack2(A0[2], A0[3]);                                          \
        ap.z = bfpack2(A1[0], A1[1]);                                          \
        ap.w = bfpack2(A1[2], A1[3]);                                          \
        bf16x8 afrag = __builtin_bit_cast(bf16x8, ap);                         \
        _Pragma("unroll")                                                      \
        for (int t = 0; t < NT; ++t) {                                         \
            bf16x8 bfrag = __builtin_bit_cast(bf16x8, B[t]);                   \
            acc[t] = __builtin_amdgcn_mfma_f32_16x16x32_bf16(afrag, bfrag,     \
                                                             acc[t], 0, 0, 0);\
        }                                                                      \
    } while (0)

    // ksteps is always even (784 = 2^4 * 7^2; nsplit in {28,8,4,2,1})
    for (int s = 0; s < ksteps; s += 2) {
        // prefetch step s+1 into (n0,n1,nb)
        const float* p1 = pA + 32;
        const uint4* q1 = pB + NT * 64;
        f32x4 n0 = ((const f32x4*)p1)[0], n1 = ((const f32x4*)p1)[1];
        uint4 nb[NT];
#pragma unroll
        for (int t = 0; t < NT; ++t) nb[t] = q1[t * 64];

        STEP(a0, a1, b);

        // prefetch step s+2 into (a0,a1,b)  (clamped on last iteration)
        int adv = (s + 2 < ksteps) ? 32 : 0;
        const float* p2 = pA + 32 + adv;
        const uint4* q2 = pB + NT * 64 + (adv ? NT * 64 : 0);
        a0 = ((const f32x4*)p2)[0];
        a1 = ((const f32x4*)p2)[1];
#pragma unroll
        for (int t = 0; t < NT; ++t) b[t] = q2[t * 64];

        STEP(n0, n1, nb);

        pA += 64;
        pB += 2 * NT * 64;
    }
#undef STEP

    // sumsq: reduce across the 4 quads that share row m; lane<16 holds rows
    sumsq += __shfl_xor(sumsq, 16, 64);
    sumsq += __shfl_xor(sumsq, 32, 64);
    if (lane < 16) fnorm2s[(size_t)sidx * B_ROWS + row] = sumsq;

    // C/D layout (16x16x32 bf16): col = lane&15, row = quad*4 + reg
    float* po = pred2 + ((size_t)sidx * B_ROWS + rowbase) * NPAD;
#pragma unroll
    for (int t = 0; t < NT; ++t) {
#pragma unroll
        for (int r = 0; r < 4; ++r) {
            po[(quad * 4 + r) * NPAD + t * 16 + m] = acc[t][r];
        }
    }
}

// ---------------- per-row split-reduce + log-softmax / NLL / argmax ----------------
// One wave per row. Sums pred2/fnorm2s over nsplit slabs, then scales by the
// two inverse norms. label dtype (int32 vs int64) dispatched at launch.
__global__ __launch_bounds__(256) void finalize_kernel(const float* __restrict__ pred2,
                                                       const float* __restrict__ fnorm2s,
                                                       const float* __restrict__ wnorm2,
                                                       const void* __restrict__ labp,
                                                       int lab64, int nsplit,
                                                       float* __restrict__ scal) {
    int gwave = (blockIdx.x * 256 + threadIdx.x) >> 6;
    int lane = threadIdx.x & 63;
    int row = gwave;
    if (row >= B_ROWS) return;

    // feature norm^2: lane s reads split s's partial, butterfly-sum
    float fn2 = (lane < nsplit) ? fnorm2s[(size_t)lane * B_ROWS + row] : 0.f;
    for (int o = 1; o < 64; o <<= 1) fn2 += __shfl_xor(fn2, o, 64);
    float finv = 10.0f / fmaxf(sqrtf(fn2), EPS);

    // logits: reduce over splits; lane owns cols {lane, lane+64}
    float s0 = 0.f, s1 = 0.f;
    for (int s = 0; s < nsplit; ++s) {
        const float* pr = pred2 + ((size_t)s * B_ROWS + row) * NPAD;
        s0 += pr[lane];
        if (lane < NPAD - 64) s1 += pr[64 + lane];
    }
    int c0 = lane, c1 = lane + 64;
    float l0 = s0 * (1.0f / fmaxf(sqrtf(wnorm2[c0]), EPS)) * finv;  // c0 < 100 always
    float l1 = -1e30f;
    if (c1 < C_CLS) l1 = s1 * (1.0f / fmaxf(sqrtf(wnorm2[c1]), EPS)) * finv;

    // argmax (first-max tie rule: keep smaller index on ties)
    float mx = l0; int am = c0;
    if (l1 > mx) { mx = l1; am = c1; }
    for (int o = 1; o < 64; o <<= 1) {
        float om = __shfl_xor(mx, o, 64);
        int   oa = __shfl_xor(am, o, 64);
        if (om > mx || (om == mx && oa < am)) { mx = om; am = oa; }
    }
    float se = expf(l0 - mx) + expf(l1 - mx);
    for (int o = 1; o < 64; o <<= 1) se += __shfl_xor(se, o, 64);

    int lab = lab64 ? (int)((const long long*)labp)[row] : ((const int*)labp)[row];
    int labc = (lab < 0) ? 0 : lab;
    float lv = (labc >= 64) ? l1 : l0;
    float ll = __shfl(lv, labc & 63, 64);

    if (lane == 0 && lab >= 0) {
        float lse = mx + logf(se);
        atomicAdd(&scal[0], lse - ll);
        atomicAdd(&scal[1], (am == lab) ? 1.f : 0.f);
        atomicAdd(&scal[2], 1.f);
    }
}

__global__ void out_kernel(const float* __restrict__ scal, float* __restrict__ out) {
    out[0] = scal[0] / fmaxf(scal[2], 1.0f);
    out[1] = scal[1] / (scal[2] + 1e-10f);
}

// Workspace layout (bytes):
//   [0, 16)              scalars         4 f32          (zeroed, 3 used)
//   [16, 464)            wnorm2          112 f32        (zeroed)
//   [1024, 5620736)      wpack bf16 B-fragments (784*7*64 uint4)
//   [5620736, 5850112)   fnorm2s         up to 28*2048 f32
//   [5850112, ...)       pred2           nsplit*2048*112 f32 (plain stores, no zeroing)
extern "C" void kernel_launch(void* const* d_in, const int* in_sizes, int n_in,
                              void* d_out, int out_size, void* d_ws, size_t ws_size,
                              hipStream_t stream) {
    const float* feat   = (const float*)d_in[0];
    const void*  label  = d_in[1];
    const float* weight = (const float*)d_in[2];
    float* out = (float*)d_out;

    char* ws = (char*)d_ws;
    float* scal    = (float*)(ws);
    float* wnorm2  = (float*)(ws + 16);
    uint4* wpack   = (uint4*)(ws + 1024);
    float* fnorm2s = (float*)(ws + 5620736);
    float* pred2   = (float*)(ws + 5850112);

    // choose split count by workspace capacity (ksteps must stay even)
    int nsplit = 28;
    {
        const int cand[5] = {28, 8, 4, 2, 1};
        for (int i = 0; i < 5; ++i) {
            nsplit = cand[i];
            size_t need = 5850112 + (size_t)nsplit * B_ROWS * NPAD * 4;
            if (need <= ws_size) break;
        }
    }
    int ksteps = KSTEPS_TOTAL / nsplit;

    int lab64 = (n_in > 1 && in_sizes[1] >= B_ROWS * 8) ? 1 : 0;

    hipMemsetAsync(ws, 0, 464, stream);
    prep_kernel<<<dim3(NPAD, 7), 256, 0, stream>>>(weight, wnorm2, (unsigned*)wpack);
    gemm_kernel<<<dim3(B_ROWS / 64, nsplit), 256, 0, stream>>>(feat, wpack, pred2, fnorm2s, ksteps);
    finalize_kernel<<<B_ROWS / 4, 256, 0, stream>>>(pred2, fnorm2s, wnorm2, label, lab64, nsplit, scal);
    out_kernel<<<1, 1, 0, stream>>>(scal, out);
}

// Round 3
// 403.185 us; speedup vs baseline: 1.0549x; 1.0340x over previous
//
#include <hip/hip_runtime.h>
#include <hip/hip_bf16.h>

// Problem constants
#define D_DIM   25088
#define B_ROWS  2048
#define C_CLS   100
#define NT      7            // 7 tiles of 16 cols -> 112 padded classes
#define NPAD    112
#define KSTEPS_TOTAL 784     // 25088 / 32
#define EPS     1e-8f

typedef __bf16 bf16x8 __attribute__((ext_vector_type(8)));
typedef float  f32x4  __attribute__((ext_vector_type(4)));
typedef float  f32x2  __attribute__((ext_vector_type(2)));

// RNE float->bf16, pack two into one dword
__device__ __forceinline__ unsigned bfpack2(float lo, float hi) {
    unsigned a = __builtin_bit_cast(unsigned, lo);
    unsigned b = __builtin_bit_cast(unsigned, hi);
    a += 0x7FFFu + ((a >> 16) & 1u);
    b += 0x7FFFu + ((b >> 16) & 1u);
    return (a >> 16) | (b & 0xFFFF0000u);
}

// async global->LDS, 16 bytes per lane; LDS dest must be wave-uniform base
__device__ __forceinline__ void gll16(const uint4* g, uint4* l) {
    __builtin_amdgcn_global_load_lds(
        (const __attribute__((address_space(1))) void*)g,
        (__attribute__((address_space(3))) void*)l, 16, 0, 0);
}

// ---------------- prep: per-class norm + pack weight into MFMA B-fragment order ----
// Grid (NPAD, 7): block (c, by) handles 7 of the 49 512-float chunks of class row c.
// wpack layout: unit u = gstep*7 + t; lane l = quad*16 + n holds
//   B[k = gstep*32 + quad*8 + j][col = t*16 + n], j=0..7, as 8 bf16 (uint4).
__global__ __launch_bounds__(256) void prep_kernel(const float* __restrict__ w,
                                                   float* __restrict__ wnorm2,
                                                   unsigned* __restrict__ wpack) {
    int c = blockIdx.x;              // 0..111
    int t = c >> 4, n = c & 15;
    bool real = (c < C_CLS);
    const float* row = w + (size_t)c * D_DIM;
    float s = 0.f;
    int i0 = blockIdx.y * 7;
#pragma unroll
    for (int ii = 0; ii < 7; ++ii) {
        int d = (i0 + ii) * 512 + threadIdx.x * 2;
        f32x2 v = {0.f, 0.f};
        if (real) v = *(const f32x2*)(row + d);
        s += v[0]*v[0] + v[1]*v[1];
        int gstep = d >> 5, r = d & 31, quad = r >> 3, j = r & 7;
        unsigned dw = bfpack2(v[0], v[1]);
        size_t idx = ((size_t)(gstep * 7 + t) * 64 + quad * 16 + n) * 4 + (j >> 1);
        wpack[idx] = dw;
    }
    if (!real) return;
    __shared__ float red[4];
    for (int o = 32; o; o >>= 1) s += __shfl_down(s, o, 64);
    if ((threadIdx.x & 63) == 0) red[threadIdx.x >> 6] = s;
    __syncthreads();
    if (threadIdx.x == 0) atomicAdd(&wnorm2[c], red[0] + red[1] + red[2] + red[3]);
}

// ---------------- main GEMM: dot(f_b, w_c) + sumsq(f_b) ----------------
// Split-K without atomics; B staged through LDS (double-buffered) via
// global_load_lds width-16: wave w stages units {w, w+4} of the NEXT step's
// 7x64x16B B-tile while computing the current step from LDS. A is register-
// prefetched one step ahead. One __syncthreads per K-step; its vmcnt/lgkm
// drain is covered because all s+1 loads issue at the START of step s.
__global__ __launch_bounds__(256, 4) void gemm_kernel(const float* __restrict__ feat,
                                                      const uint4* __restrict__ wpack,
                                                      float* __restrict__ pred2,
                                                      float* __restrict__ fnorm2s,
                                                      int ksteps) {
    __shared__ uint4 bst[2][NT * 64];   // 2 x 7168 B

    int tid  = threadIdx.x;
    int wave = tid >> 6, lane = tid & 63;
    int m = lane & 15, quad = lane >> 4;
    int rowbase = blockIdx.x * 64 + wave * 16;
    int row = rowbase + m;
    int sidx = blockIdx.y;
    int gstep0 = sidx * ksteps;

    const float* pA = feat + (size_t)row * D_DIM + gstep0 * 32 + quad * 8;
    const uint4* qB = wpack + (size_t)gstep0 * NT * 64;   // step-s global B base

    f32x4 acc[NT];
#pragma unroll
    for (int t = 0; t < NT; ++t) acc[t] = (f32x4){0.f,0.f,0.f,0.f};
    float sumsq = 0.f;

    // prologue: stage B[0] into bst[0], load A[0] into regs
    gll16(qB + wave * 64 + lane, &bst[0][wave * 64]);
    if (wave < 3) gll16(qB + (wave + 4) * 64 + lane, &bst[0][(wave + 4) * 64]);
    f32x4 a0 = ((const f32x4*)pA)[0], a1 = ((const f32x4*)pA)[1];
    __syncthreads();

    int cur = 0;
    for (int s = 0; s < ksteps; ++s) {
        // issue next step's B staging + A loads first (they drain at the barrier)
        const uint4* qn = qB + NT * 64;
        if (s + 1 < ksteps) {
            gll16(qn + wave * 64 + lane, &bst[cur ^ 1][wave * 64]);
            if (wave < 3) gll16(qn + (wave + 4) * 64 + lane, &bst[cur ^ 1][(wave + 4) * 64]);
        }
        const float* pn = pA + ((s + 1 < ksteps) ? 32 : 0);
        f32x4 n0 = ((const f32x4*)pn)[0];
        f32x4 n1 = ((const f32x4*)pn)[1];

        // compute step s from regs (A) + LDS (B)
        sumsq += a0[0]*a0[0] + a0[1]*a0[1] + a0[2]*a0[2] + a0[3]*a0[3]
               + a1[0]*a1[0] + a1[1]*a1[1] + a1[2]*a1[2] + a1[3]*a1[3];
        uint4 ap;
        ap.x = bfpack2(a0[0], a0[1]);
        ap.y = bfpack2(a0[2], a0[3]);
        ap.z = bfpack2(a1[0], a1[1]);
        ap.w = bfpack2(a1[2], a1[3]);
        bf16x8 afrag = __builtin_bit_cast(bf16x8, ap);
#pragma unroll
        for (int t = 0; t < NT; ++t) {
            uint4 bw = bst[cur][t * 64 + lane];
            acc[t] = __builtin_amdgcn_mfma_f32_16x16x32_bf16(
                afrag, __builtin_bit_cast(bf16x8, bw), acc[t], 0, 0, 0);
        }

        a0 = n0; a1 = n1;
        pA += 32; qB += NT * 64;
        __syncthreads();
        cur ^= 1;
    }

    // sumsq: reduce across the 4 quads that share row m; lane<16 holds rows
    sumsq += __shfl_xor(sumsq, 16, 64);
    sumsq += __shfl_xor(sumsq, 32, 64);
    if (lane < 16) fnorm2s[(size_t)sidx * B_ROWS + row] = sumsq;

    // C/D layout (16x16x32 bf16): col = lane&15, row = quad*4 + reg
    float* po = pred2 + ((size_t)sidx * B_ROWS + rowbase) * NPAD;
#pragma unroll
    for (int t = 0; t < NT; ++t) {
#pragma unroll
        for (int r = 0; r < 4; ++r) {
            po[(quad * 4 + r) * NPAD + t * 16 + m] = acc[t][r];
        }
    }
}

// ---------------- per-row split-reduce + log-softmax / NLL / argmax ----------------
// One wave per row. Sums pred2/fnorm2s over nsplit slabs, then scales by the
// two inverse norms. label dtype (int32 vs int64) dispatched at launch.
__global__ __launch_bounds__(256) void finalize_kernel(const float* __restrict__ pred2,
                                                       const float* __restrict__ fnorm2s,
                                                       const float* __restrict__ wnorm2,
                                                       const void* __restrict__ labp,
                                                       int lab64, int nsplit,
                                                       float* __restrict__ scal) {
    int gwave = (blockIdx.x * 256 + threadIdx.x) >> 6;
    int lane = threadIdx.x & 63;
    int row = gwave;
    if (row >= B_ROWS) return;

    // feature norm^2: lane s reads split s's partial, butterfly-sum
    float fn2 = (lane < nsplit) ? fnorm2s[(size_t)lane * B_ROWS + row] : 0.f;
    for (int o = 1; o < 64; o <<= 1) fn2 += __shfl_xor(fn2, o, 64);
    float finv = 10.0f / fmaxf(sqrtf(fn2), EPS);

    // logits: reduce over splits; lane owns cols {lane, lane+64}
    float s0 = 0.f, s1 = 0.f;
    for (int s = 0; s < nsplit; ++s) {
        const float* pr = pred2 + ((size_t)s * B_ROWS + row) * NPAD;
        s0 += pr[lane];
        if (lane < NPAD - 64) s1 += pr[64 + lane];
    }
    int c0 = lane, c1 = lane + 64;
    float l0 = s0 * (1.0f / fmaxf(sqrtf(wnorm2[c0]), EPS)) * finv;  // c0 < 100 always
    float l1 = -1e30f;
    if (c1 < C_CLS) l1 = s1 * (1.0f / fmaxf(sqrtf(wnorm2[c1]), EPS)) * finv;

    // argmax (first-max tie rule: keep smaller index on ties)
    float mx = l0; int am = c0;
    if (l1 > mx) { mx = l1; am = c1; }
    for (int o = 1; o < 64; o <<= 1) {
        float om = __shfl_xor(mx, o, 64);
        int   oa = __shfl_xor(am, o, 64);
        if (om > mx || (om == mx && oa < am)) { mx = om; am = oa; }
    }
    float se = expf(l0 - mx) + expf(l1 - mx);
    for (int o = 1; o < 64; o <<= 1) se += __shfl_xor(se, o, 64);

    int lab = lab64 ? (int)((const long long*)labp)[row] : ((const int*)labp)[row];
    int labc = (lab < 0) ? 0 : lab;
    float lv = (labc >= 64) ? l1 : l0;
    float ll = __shfl(lv, labc & 63, 64);

    if (lane == 0 && lab >= 0) {
        float lse = mx + logf(se);
        atomicAdd(&scal[0], lse - ll);
        atomicAdd(&scal[1], (am == lab) ? 1.f : 0.f);
        atomicAdd(&scal[2], 1.f);
    }
}

__global__ void out_kernel(const float* __restrict__ scal, float* __restrict__ out) {
    out[0] = scal[0] / fmaxf(scal[2], 1.0f);
    out[1] = scal[1] / (scal[2] + 1e-10f);
}

// Workspace layout (bytes):
//   [0, 16)              scalars         4 f32          (zeroed, 3 used)
//   [16, 464)            wnorm2          112 f32        (zeroed)
//   [1024, 5620736)      wpack bf16 B-fragments (784*7*64 uint4)
//   [5620736, 5850112)   fnorm2s         up to 28*2048 f32
//   [5850112, ...)       pred2           nsplit*2048*112 f32 (plain stores, no zeroing)
extern "C" void kernel_launch(void* const* d_in, const int* in_sizes, int n_in,
                              void* d_out, int out_size, void* d_ws, size_t ws_size,
                              hipStream_t stream) {
    const float* feat   = (const float*)d_in[0];
    const void*  label  = d_in[1];
    const float* weight = (const float*)d_in[2];
    float* out = (float*)d_out;

    char* ws = (char*)d_ws;
    float* scal    = (float*)(ws);
    float* wnorm2  = (float*)(ws + 16);
    uint4* wpack   = (uint4*)(ws + 1024);
    float* fnorm2s = (float*)(ws + 5620736);
    float* pred2   = (float*)(ws + 5850112);

    // choose split count by workspace capacity
    int nsplit = 28;
    {
        const int cand[5] = {28, 8, 4, 2, 1};
        for (int i = 0; i < 5; ++i) {
            nsplit = cand[i];
            size_t need = 5850112 + (size_t)nsplit * B_ROWS * NPAD * 4;
            if (need <= ws_size) break;
        }
    }
    int ksteps = KSTEPS_TOTAL / nsplit;

    int lab64 = (n_in > 1 && in_sizes[1] >= B_ROWS * 8) ? 1 : 0;

    hipMemsetAsync(ws, 0, 464, stream);
    prep_kernel<<<dim3(NPAD, 7), 256, 0, stream>>>(weight, wnorm2, (unsigned*)wpack);
    gemm_kernel<<<dim3(B_ROWS / 64, nsplit), 256, 0, stream>>>(feat, wpack, pred2, fnorm2s, ksteps);
    finalize_kernel<<<B_ROWS / 4, 256, 0, stream>>>(pred2, fnorm2s, wnorm2, label, lab64, nsplit, scal);
    out_kernel<<<1, 1, 0, stream>>>(scal, out);
}

// Round 4
// 325.732 us; speedup vs baseline: 1.3057x; 1.2378x over previous
//
#include <hip/hip_runtime.h>
#include <hip/hip_bf16.h>

// Problem constants
#define D_DIM   25088
#define B_ROWS  2048
#define C_CLS   100
#define NT      7            // 7 tiles of 16 cols -> 112 padded classes
#define NPAD    112
#define KSTEPS_TOTAL 784     // 25088 / 32
#define EPS     1e-8f

typedef __bf16 bf16x8 __attribute__((ext_vector_type(8)));
typedef float  f32x4  __attribute__((ext_vector_type(4)));
typedef float  f32x2  __attribute__((ext_vector_type(2)));

// RNE float->bf16, pack two into one dword
__device__ __forceinline__ unsigned bfpack2(float lo, float hi) {
    unsigned a = __builtin_bit_cast(unsigned, lo);
    unsigned b = __builtin_bit_cast(unsigned, hi);
    a += 0x7FFFu + ((a >> 16) & 1u);
    b += 0x7FFFu + ((b >> 16) & 1u);
    return (a >> 16) | (b & 0xFFFF0000u);
}

// async global->LDS, 16 bytes per lane; LDS dest must be wave-uniform base
__device__ __forceinline__ void gll16(const uint4* g, uint4* l) {
    __builtin_amdgcn_global_load_lds(
        (const __attribute__((address_space(1))) void*)g,
        (__attribute__((address_space(3))) void*)l, 16, 0, 0);
}

// ---------------- prep: per-class norm + pack weight into MFMA B-fragment order ----
// Grid (NPAD, 7): block (c, by) handles 7 of the 49 512-float chunks of class row c.
// wpack layout: unit u = gstep*7 + t; lane l = quad*16 + n holds
//   B[k = gstep*32 + quad*8 + j][col = t*16 + n], j=0..7, as 8 bf16 (uint4).
__global__ __launch_bounds__(256) void prep_kernel(const float* __restrict__ w,
                                                   float* __restrict__ wnorm2,
                                                   unsigned* __restrict__ wpack) {
    int c = blockIdx.x;              // 0..111
    int t = c >> 4, n = c & 15;
    bool real = (c < C_CLS);
    const float* row = w + (size_t)c * D_DIM;
    float s = 0.f;
    int i0 = blockIdx.y * 7;
#pragma unroll
    for (int ii = 0; ii < 7; ++ii) {
        int d = (i0 + ii) * 512 + threadIdx.x * 2;
        f32x2 v = {0.f, 0.f};
        if (real) v = *(const f32x2*)(row + d);
        s += v[0]*v[0] + v[1]*v[1];
        int gstep = d >> 5, r = d & 31, quad = r >> 3, j = r & 7;
        unsigned dw = bfpack2(v[0], v[1]);
        size_t idx = ((size_t)(gstep * 7 + t) * 64 + quad * 16 + n) * 4 + (j >> 1);
        wpack[idx] = dw;
    }
    if (!real) return;
    __shared__ float red[4];
    for (int o = 32; o; o >>= 1) s += __shfl_down(s, o, 64);
    if ((threadIdx.x & 63) == 0) red[threadIdx.x >> 6] = s;
    __syncthreads();
    if (threadIdx.x == 0) atomicAdd(&wnorm2[c], red[0] + red[1] + red[2] + red[3]);
}

// ---------------- main GEMM: dot(f_b, w_c) + sumsq(f_b) ----------------
// Split-K without atomics; B staged through LDS (double-buffered) via
// global_load_lds width-16: wave w stages units {w, w+4} of the NEXT step's
// 7x64x16B B-tile while computing the current step from LDS. A is register-
// prefetched one step ahead. One __syncthreads per K-step.
__global__ __launch_bounds__(256, 4) void gemm_kernel(const float* __restrict__ feat,
                                                      const uint4* __restrict__ wpack,
                                                      float* __restrict__ pred2,
                                                      float* __restrict__ fnorm2s,
                                                      int ksteps) {
    __shared__ uint4 bst[2][NT * 64];   // 2 x 7168 B

    int tid  = threadIdx.x;
    int wave = tid >> 6, lane = tid & 63;
    int m = lane & 15, quad = lane >> 4;
    int rowbase = blockIdx.x * 64 + wave * 16;
    int row = rowbase + m;
    int sidx = blockIdx.y;
    int gstep0 = sidx * ksteps;

    const float* pA = feat + (size_t)row * D_DIM + gstep0 * 32 + quad * 8;
    const uint4* qB = wpack + (size_t)gstep0 * NT * 64;   // step-s global B base

    f32x4 acc[NT];
#pragma unroll
    for (int t = 0; t < NT; ++t) acc[t] = (f32x4){0.f,0.f,0.f,0.f};
    float sumsq = 0.f;

    // prologue: stage B[0] into bst[0], load A[0] into regs
    gll16(qB + wave * 64 + lane, &bst[0][wave * 64]);
    if (wave < 3) gll16(qB + (wave + 4) * 64 + lane, &bst[0][(wave + 4) * 64]);
    f32x4 a0 = ((const f32x4*)pA)[0], a1 = ((const f32x4*)pA)[1];
    __syncthreads();

    int cur = 0;
    for (int s = 0; s < ksteps; ++s) {
        // issue next step's B staging + A loads first (they drain at the barrier)
        const uint4* qn = qB + NT * 64;
        if (s + 1 < ksteps) {
            gll16(qn + wave * 64 + lane, &bst[cur ^ 1][wave * 64]);
            if (wave < 3) gll16(qn + (wave + 4) * 64 + lane, &bst[cur ^ 1][(wave + 4) * 64]);
        }
        const float* pn = pA + ((s + 1 < ksteps) ? 32 : 0);
        f32x4 n0 = ((const f32x4*)pn)[0];
        f32x4 n1 = ((const f32x4*)pn)[1];

        // compute step s from regs (A) + LDS (B)
        sumsq += a0[0]*a0[0] + a0[1]*a0[1] + a0[2]*a0[2] + a0[3]*a0[3]
               + a1[0]*a1[0] + a1[1]*a1[1] + a1[2]*a1[2] + a1[3]*a1[3];
        uint4 ap;
        ap.x = bfpack2(a0[0], a0[1]);
        ap.y = bfpack2(a0[2], a0[3]);
        ap.z = bfpack2(a1[0], a1[1]);
        ap.w = bfpack2(a1[2], a1[3]);
        bf16x8 afrag = __builtin_bit_cast(bf16x8, ap);
#pragma unroll
        for (int t = 0; t < NT; ++t) {
            uint4 bw = bst[cur][t * 64 + lane];
            acc[t] = __builtin_amdgcn_mfma_f32_16x16x32_bf16(
                afrag, __builtin_bit_cast(bf16x8, bw), acc[t], 0, 0, 0);
        }

        a0 = n0; a1 = n1;
        pA += 32; qB += NT * 64;
        __syncthreads();
        cur ^= 1;
    }

    // sumsq: reduce across the 4 quads that share row m; lane<16 holds rows
    sumsq += __shfl_xor(sumsq, 16, 64);
    sumsq += __shfl_xor(sumsq, 32, 64);
    if (lane < 16) fnorm2s[(size_t)sidx * B_ROWS + row] = sumsq;

    // C/D layout (16x16x32 bf16): col = lane&15, row = quad*4 + reg
    float* po = pred2 + ((size_t)sidx * B_ROWS + rowbase) * NPAD;
#pragma unroll
    for (int t = 0; t < NT; ++t) {
#pragma unroll
        for (int r = 0; r < 4; ++r) {
            po[(quad * 4 + r) * NPAD + t * 16 + m] = acc[t][r];
        }
    }
}

// ---------------- per-row split-reduce + log-softmax / NLL / argmax ----------------
// One wave per row. Sums pred2/fnorm2s over nsplit slabs, scales by the two
// inverse norms, then writes ONE float4{nll, correct, valid} per row with a
// plain store — NO global atomics (the previous 6144 same-line atomicAdds
// were a ~100 µs serialization storm).
__global__ __launch_bounds__(256) void finalize_kernel(const float* __restrict__ pred2,
                                                       const float* __restrict__ fnorm2s,
                                                       const float* __restrict__ wnorm2,
                                                       const void* __restrict__ labp,
                                                       int lab64, int nsplit,
                                                       float4* __restrict__ rowred) {
    int gwave = (blockIdx.x * 256 + threadIdx.x) >> 6;
    int lane = threadIdx.x & 63;
    int row = gwave;
    if (row >= B_ROWS) return;

    // feature norm^2: lane s reads split s's partial, butterfly-sum
    float fn2 = (lane < nsplit) ? fnorm2s[(size_t)lane * B_ROWS + row] : 0.f;
    for (int o = 1; o < 64; o <<= 1) fn2 += __shfl_xor(fn2, o, 64);
    float finv = 10.0f / fmaxf(sqrtf(fn2), EPS);

    // logits: reduce over splits; lane owns cols {lane, lane+64}
    float s0 = 0.f, s1 = 0.f;
    for (int s = 0; s < nsplit; ++s) {
        const float* pr = pred2 + ((size_t)s * B_ROWS + row) * NPAD;
        s0 += pr[lane];
        if (lane < NPAD - 64) s1 += pr[64 + lane];
    }
    int c0 = lane, c1 = lane + 64;
    float l0 = s0 * (1.0f / fmaxf(sqrtf(wnorm2[c0]), EPS)) * finv;  // c0 < 100 always
    float l1 = -1e30f;
    if (c1 < C_CLS) l1 = s1 * (1.0f / fmaxf(sqrtf(wnorm2[c1]), EPS)) * finv;

    // argmax (first-max tie rule: keep smaller index on ties)
    float mx = l0; int am = c0;
    if (l1 > mx) { mx = l1; am = c1; }
    for (int o = 1; o < 64; o <<= 1) {
        float om = __shfl_xor(mx, o, 64);
        int   oa = __shfl_xor(am, o, 64);
        if (om > mx || (om == mx && oa < am)) { mx = om; am = oa; }
    }
    float se = expf(l0 - mx) + expf(l1 - mx);
    for (int o = 1; o < 64; o <<= 1) se += __shfl_xor(se, o, 64);

    int lab = lab64 ? (int)((const long long*)labp)[row] : ((const int*)labp)[row];
    int labc = (lab < 0) ? 0 : lab;
    float lv = (labc >= 64) ? l1 : l0;
    float ll = __shfl(lv, labc & 63, 64);

    if (lane == 0) {
        float lse = mx + logf(se);
        bool valid = (lab >= 0);
        float4 o;
        o.x = valid ? (lse - ll) : 0.f;          // masked nll
        o.y = (valid && am == lab) ? 1.f : 0.f;  // masked correct
        o.z = valid ? 1.f : 0.f;                 // valid count
        o.w = 0.f;
        rowred[row] = o;
    }
}

// ---------------- single-block final reduction: 2048 float4 -> loss, acc ----------------
__global__ __launch_bounds__(256) void reduce_kernel(const float4* __restrict__ rowred,
                                                     float* __restrict__ out) {
    float nll = 0.f, cor = 0.f, val = 0.f;
    for (int i = threadIdx.x; i < B_ROWS; i += 256) {
        float4 v = rowred[i];
        nll += v.x; cor += v.y; val += v.z;
    }
    for (int o = 32; o; o >>= 1) {
        nll += __shfl_down(nll, o, 64);
        cor += __shfl_down(cor, o, 64);
        val += __shfl_down(val, o, 64);
    }
    __shared__ float r[3][4];
    int w = threadIdx.x >> 6;
    if ((threadIdx.x & 63) == 0) { r[0][w] = nll; r[1][w] = cor; r[2][w] = val; }
    __syncthreads();
    if (threadIdx.x == 0) {
        float N = r[0][0] + r[0][1] + r[0][2] + r[0][3];
        float C = r[1][0] + r[1][1] + r[1][2] + r[1][3];
        float V = r[2][0] + r[2][1] + r[2][2] + r[2][3];
        out[0] = N / fmaxf(V, 1.0f);
        out[1] = C / (V + 1e-10f);
    }
}

// Workspace layout (bytes):
//   [0, 448)             wnorm2          112 f32        (zeroed)
//   [512, 33280)         rowred          2048 float4    (plain stores, no zeroing)
//   [33792, 5653504)     wpack bf16 B-fragments (784*7*64 uint4)
//   [5653504, 5882880)   fnorm2s         up to 28*2048 f32
//   [5882880, ...)       pred2           nsplit*2048*112 f32 (plain stores, no zeroing)
extern "C" void kernel_launch(void* const* d_in, const int* in_sizes, int n_in,
                              void* d_out, int out_size, void* d_ws, size_t ws_size,
                              hipStream_t stream) {
    const float* feat   = (const float*)d_in[0];
    const void*  label  = d_in[1];
    const float* weight = (const float*)d_in[2];
    float* out = (float*)d_out;

    char* ws = (char*)d_ws;
    float*  wnorm2  = (float*)(ws);
    float4* rowred  = (float4*)(ws + 512);
    uint4*  wpack   = (uint4*)(ws + 33792);
    float*  fnorm2s = (float*)(ws + 5653504);
    float*  pred2   = (float*)(ws + 5882880);

    // choose split count by workspace capacity
    int nsplit = 28;
    {
        const int cand[5] = {28, 8, 4, 2, 1};
        for (int i = 0; i < 5; ++i) {
            nsplit = cand[i];
            size_t need = 5882880 + (size_t)nsplit * B_ROWS * NPAD * 4;
            if (need <= ws_size) break;
        }
    }
    int ksteps = KSTEPS_TOTAL / nsplit;

    int lab64 = (n_in > 1 && in_sizes[1] >= B_ROWS * 8) ? 1 : 0;

    hipMemsetAsync(ws, 0, 448, stream);
    prep_kernel<<<dim3(NPAD, 7), 256, 0, stream>>>(weight, wnorm2, (unsigned*)wpack);
    gemm_kernel<<<dim3(B_ROWS / 64, nsplit), 256, 0, stream>>>(feat, wpack, pred2, fnorm2s, ksteps);
    finalize_kernel<<<B_ROWS / 4, 256, 0, stream>>>(pred2, fnorm2s, wnorm2, label, lab64, nsplit, rowred);
    reduce_kernel<<<1, 256, 0, stream>>>(rowred, out);
}